// Round 12
// baseline (24388.148 us; speedup 1.0000x reference)
//
#include <hip/hip_runtime.h>
#include <cmath>

// ---------------------------------------------------------------------------
// GridGRU on MI355X. Round 12: r11 structure + relaxed device-scope ATOMIC
// barrier (arrive=fetch_add(1), poll=fetch_add(0)), plus two diagnostic
// dispatches (D1 bare barrier, D2 barrier+exchange) to split the ~20us hop.
// N=32, T=512, D=H=1024. weight (2048,6144) row-major f32, bias 6144.
// ---------------------------------------------------------------------------

#define LDW 6144
#define CT 32                      // timesteps per segment (16 segments)
typedef float  f32x4 __attribute__((ext_vector_type(4)));
typedef short  s16x8 __attribute__((ext_vector_type(8)));
typedef unsigned u32x4 __attribute__((ext_vector_type(4)));

__device__ __forceinline__ float sigf(float v){ return 1.f/(1.f+__expf(-v)); }
__device__ __forceinline__ unsigned short f2b(float f){
    unsigned u = __float_as_uint(f);
    return (unsigned short)((u + 0x7FFFu + ((u>>16)&1u)) >> 16);
}
__device__ __forceinline__ float b2f(unsigned short u){
    return __uint_as_float(((unsigned)u) << 16);
}

// ---- device-scope (sc1) write-through helpers -----------------------------
__device__ __forceinline__ void st_dev_u32x4(unsigned* p, u32x4 v){
    asm volatile("global_store_dwordx4 %0, %1, off sc1"
                 :: "v"(p), "v"(v) : "memory");
}

// ---- atomic barrier primitives (relaxed, device scope) --------------------
__device__ __forceinline__ void bar_arrive(unsigned* flag){
    __hip_atomic_fetch_add(flag, 1u, __ATOMIC_RELAXED, __HIP_MEMORY_SCOPE_AGENT);
}
__device__ __forceinline__ void bar_wait(unsigned* flag, unsigned target){
    while (__hip_atomic_fetch_add(flag, 0u, __ATOMIC_RELAXED,
                                  __HIP_MEMORY_SCOPE_AGENT) < target)
        __builtin_amdgcn_s_sleep(1);
}

// ---- WT[j][k] = bf16(weight[k][j]); j<6144, k<2048 -------------------------
__global__ __launch_bounds__(256)
void k_wt(const float* __restrict__ w, unsigned short* __restrict__ wt)
{
    __shared__ float t[64][65];
    const int j0 = blockIdx.x*64, k0 = blockIdx.y*64;
    for (int i = threadIdx.x; i < 4096; i += 256) {
        int r = i>>6, c = i&63;
        t[r][c] = w[(size_t)(k0+r)*LDW + j0 + c];
    }
    __syncthreads();
    for (int i = threadIdx.x; i < 4096; i += 256) {
        int jr = i>>6, kc = i&63;
        wt[(size_t)(j0+jr)*2048 + k0 + kc] = f2b(t[kc][jr]);
    }
}

// ---- Wlo[j][k] = bf16-residual of weight[1024+k][j]; j<3072, k<1024 --------
__global__ __launch_bounds__(256)
void k_wlo(const float* __restrict__ w, unsigned short* __restrict__ wlo)
{
    __shared__ float t[64][65];
    const int j0 = blockIdx.x*64, k0 = blockIdx.y*64;
    for (int i = threadIdx.x; i < 4096; i += 256) {
        int r = i>>6, c = i&63;
        t[r][c] = w[(size_t)(1024+k0+r)*LDW + j0 + c];
    }
    __syncthreads();
    for (int i = threadIdx.x; i < 4096; i += 256) {
        int jr = i>>6, kc = i&63;
        float v = t[kc][jr];
        unsigned short hi = f2b(v);
        wlo[(size_t)(j0+jr)*1024 + k0 + kc] = f2b(v - b2f(hi));
    }
}

// ---- x (f32) -> bf16 -------------------------------------------------------
__global__ __launch_bounds__(256)
void k_xbf(const float* __restrict__ x, unsigned short* __restrict__ o)
{
    long i = ((long)blockIdx.x*256 + threadIdx.x)*4;
    float4 v = *(const float4*)&x[i];
    ushort4 r = { f2b(v.x), f2b(v.y), f2b(v.z), f2b(v.w) };
    *(ushort4*)&o[i] = r;
}

// ---------------------------------------------------------------------------
// bf16 MFMA GEMM (validated rounds 3-11).
// ---------------------------------------------------------------------------
template<int AMODE, int EMODE>
__global__ __launch_bounds__(256)
void gemm_mfma(const unsigned short* __restrict__ A1,
               const unsigned short* __restrict__ A2,
               const unsigned short* __restrict__ Bw,
               float* __restrict__ C, int ldc,
               const float* __restrict__ bias,
               const float* __restrict__ X,
               float* __restrict__ UD,
               unsigned short* __restrict__ RX,
               int K, int t0)
{
    __shared__ unsigned short Als[128*32];
    __shared__ unsigned short Bls[128*32];
    const int tid = threadIdx.x;
    const int m_base = blockIdx.y*128;
    const int n_base = blockIdx.x*128;
    const int row0 = tid>>2, row1 = row0+64, quad = tid&3;
    const int wv = tid>>6, lane = tid&63;
    const int wr = (wv>>1)*64, wc = (wv&1)*64;
    const int l15 = lane&15, l4 = lane>>4;

    f32x4 acc[4][4] = {};

    for (int k0 = 0; k0 < K; k0 += 32) {
        const int kq = k0 + quad*8;
        s16x8 a0, a1, b0, b1;
        {
            long r0 = m_base + row0, r1 = m_base + row1;
            const unsigned short *p0, *p1;
            if (AMODE == 1) {
                long g0 = (r0>>5)*512 + t0 + (r0&31);
                long g1 = (r1>>5)*512 + t0 + (r1&31);
                p0 = A1 + g0*1024 + kq; p1 = A1 + g1*1024 + kq;
            } else if (AMODE == 2 && k0 >= 1024) {
                size_t o0 = ((size_t)(r0 & 511)*32 + (r0 >> 9))*1024 + (kq-1024);
                size_t o1 = ((size_t)(r1 & 511)*32 + (r1 >> 9))*1024 + (kq-1024);
                p0 = A2 + o0; p1 = A2 + o1;
            } else {
                p0 = A1 + r0*1024 + kq; p1 = A1 + r1*1024 + kq;
            }
            a0 = *(const s16x8*)p0; a1 = *(const s16x8*)p1;
        }
        b0 = *(const s16x8*)(Bw + (size_t)(n_base+row0)*2048 + kq);
        b1 = *(const s16x8*)(Bw + (size_t)(n_base+row1)*2048 + kq);
        __syncthreads();
        *(s16x8*)&Als[row0*32 + quad*8] = a0;
        *(s16x8*)&Als[row1*32 + quad*8] = a1;
        *(s16x8*)&Bls[row0*32 + quad*8] = b0;
        *(s16x8*)&Bls[row1*32 + quad*8] = b1;
        __syncthreads();
        s16x8 af[4], bfr[4];
#pragma unroll
        for (int i = 0; i < 4; ++i) {
            af[i]  = *(const s16x8*)&Als[(wr + i*16 + l15)*32 + l4*8];
            bfr[i] = *(const s16x8*)&Bls[(wc + i*16 + l15)*32 + l4*8];
        }
#pragma unroll
        for (int mi = 0; mi < 4; ++mi)
#pragma unroll
            for (int ni = 0; ni < 4; ++ni)
                acc[mi][ni] = __builtin_amdgcn_mfma_f32_16x16x32_bf16(
                    af[mi], bfr[ni], acc[mi][ni], 0, 0, 0);
    }

#pragma unroll
    for (int mi = 0; mi < 4; ++mi)
#pragma unroll
    for (int ni = 0; ni < 4; ++ni)
#pragma unroll
    for (int q = 0; q < 4; ++q) {
        int row = m_base + wr + mi*16 + l4*4 + q;
        int col = n_base + wc + ni*16 + l15;
        float v = acc[mi][ni][q] + bias[col];
        if (EMODE == 0) {
            C[(size_t)row*ldc + col] = v;
        } else if (EMODE == 1) {
            float s = sigf(v);
            if (col < 1024) {
                UD[(size_t)row*1024 + col] = s;
            } else {
                int jj = col - 1024;
                RX[(size_t)row*1024 + jj] = f2b(s * X[(size_t)row*1024 + jj]);
            }
        } else {
            float hc = tanhf(v);
            float xv = X[(size_t)row*1024 + col];
            float ud = UD[(size_t)row*1024 + col];
            C[(size_t)row*1024 + col] = xv + ud*(hc - xv);
        }
    }
}

// ---------------------------------------------------------------------------
// Sample-decomposed persistent scan (r11 structure), ATOMIC barrier.
// ---------------------------------------------------------------------------
__global__ __launch_bounds__(512)
void scan_mfma5(const float* __restrict__ chunk,
                const unsigned short* __restrict__ WT,
                const unsigned short* __restrict__ Wlo,
                const float* __restrict__ prev_ht,
                unsigned* __restrict__ hX,          // [CT][4][1024][8] u32
                unsigned* __restrict__ rhX,         // [CT][4][1024][8] u32
                unsigned short* __restrict__ htR,   // [(t*32+n)*1024+j] bf16
                float* __restrict__ hper,           // [b][8n][128] f32
                unsigned* __restrict__ flags,
                int t0, int bidx0)
{
    __shared__ unsigned short shi[16*1032];
    __shared__ unsigned short slo[16*1032];
    __shared__ float hf32[1024];
    __shared__ float uls [1024];
    const int tid = threadIdx.x;
    const int b   = blockIdx.x;
    const int p   = b & 7, g = b >> 3;
    const int w   = tid >> 6;
    const int lane= tid & 63;
    const int l15 = lane & 15, l4 = lane >> 4;
    const int cb  = p * 128;
    const int nsb = g * 8;
    unsigned bidx = (unsigned)bidx0;
    unsigned* ownf = &flags[(unsigned)b*32];

    for (int i = tid; i < 8*1032; i += 512) { shi[8*1032 + i] = 0; slo[8*1032 + i] = 0; }
    for (int i = tid; i < 1024; i += 512) {
        int nl = i >> 7, jl = i & 127;
        hf32[i] = (t0 == 0) ? prev_ht[(size_t)(nsb+nl)*1024 + cb + jl]
                            : hper[(size_t)b*1024 + i];
    }

    for (int tl = 0; tl < CT; ++tl) {
        const int t = t0 + tl;

        // ---- stage h ----------------------------------------------------
        if (t == 0) {
#pragma unroll 2
            for (int it = 0; it < 4; ++it) {
                int idx = tid + it*512;
                int nl = idx >> 8, k4 = (idx & 255) * 4;
                f32x4 v = *(const f32x4*)&prev_ht[(size_t)(nsb+nl)*1024 + k4];
#pragma unroll
                for (int e = 0; e < 4; ++e) {
                    unsigned short hi = f2b(v[e]);
                    shi[nl*1032 + k4 + e] = hi;
                    slo[nl*1032 + k4 + e] = f2b(v[e] - b2f(hi));
                }
            }
        } else {
            int slot = (tl == 0) ? (CT-1) : (tl-1);
            const unsigned* src = hX + ((size_t)slot*4 + g)*8192;
#pragma unroll 2
            for (int it = 0; it < 4; ++it) {
                int idx = tid + it*512;
                u32x4 v = *(const u32x4*)&src[idx*4];
                int k = idx >> 1, n0 = (idx & 1) * 4;
#pragma unroll
                for (int e = 0; e < 4; ++e) {
                    shi[(n0+e)*1032 + k] = (unsigned short)(v[e] >> 16);
                    slo[(n0+e)*1032 + k] = (unsigned short)(v[e] & 0xffffu);
                }
            }
        }
        __syncthreads();

        // ---- phase A: own u-cols + r-cols -------------------------------
        {
            f32x4 accU = {0,0,0,0}, accR = {0,0,0,0};
            const unsigned short* bhU = WT  + (size_t)(cb + w*16 + l15)*2048 + 1024 + l4*8;
            const unsigned short* blU = Wlo + (size_t)(cb + w*16 + l15)*1024 + l4*8;
            const unsigned short* bhR = WT  + (size_t)(1024 + cb + w*16 + l15)*2048 + 1024 + l4*8;
            const unsigned short* blR = Wlo + (size_t)(1024 + cb + w*16 + l15)*1024 + l4*8;
            for (int kq = 0; kq < 32; ++kq) {
                const int ka = kq*32 + l4*8;
                s16x8 ah = *(const s16x8*)&shi[l15*1032 + ka];
                s16x8 al = *(const s16x8*)&slo[l15*1032 + ka];
                s16x8 buh = *(const s16x8*)(bhU + kq*32);
                s16x8 bul = *(const s16x8*)(blU + kq*32);
                s16x8 brh = *(const s16x8*)(bhR + kq*32);
                s16x8 brl = *(const s16x8*)(blR + kq*32);
                accU = __builtin_amdgcn_mfma_f32_16x16x32_bf16(ah, buh, accU, 0,0,0);
                accU = __builtin_amdgcn_mfma_f32_16x16x32_bf16(al, buh, accU, 0,0,0);
                accU = __builtin_amdgcn_mfma_f32_16x16x32_bf16(ah, bul, accU, 0,0,0);
                accR = __builtin_amdgcn_mfma_f32_16x16x32_bf16(ah, brh, accR, 0,0,0);
                accR = __builtin_amdgcn_mfma_f32_16x16x32_bf16(al, brh, accR, 0,0,0);
                accR = __builtin_amdgcn_mfma_f32_16x16x32_bf16(ah, brl, accR, 0,0,0);
            }
            if (l4 < 2) {
                const int jl = w*16 + l15;
                const int k  = cb + jl;
                u32x4 pk;
#pragma unroll
                for (int q = 0; q < 4; ++q) {
                    int nl = l4*4 + q;
                    size_t crow = (size_t)(((nsb+nl)<<5) + tl)*3072;
                    float vu = accU[q] + chunk[crow + cb + jl];
                    uls[nl*128 + jl] = sigf(vu);
                    float vr = accR[q] + chunk[crow + 1024 + k];
                    float s  = sigf(vr);
                    float hv = b2f(shi[nl*1032 + k]) + b2f(slo[nl*1032 + k]);
                    float rh = s * hv;
                    unsigned short hi = f2b(rh);
                    unsigned short lo = f2b(rh - b2f(hi));
                    pk[q] = ((unsigned)hi << 16) | lo;
                }
                st_dev_u32x4(&rhX[(((size_t)tl*4 + g)*1024 + k)*8 + l4*4], pk);
            }
        }
        // ---- barrier 1 (atomic, group of 8) -----------------------------
        asm volatile("s_waitcnt vmcnt(0)" ::: "memory");
        __syncthreads(); ++bidx;
        if (tid == 0) bar_arrive(ownf);
        if (tid < 8) bar_wait(&flags[(unsigned)(g*8 + tid)*32], bidx);
        __syncthreads();

        // ---- stage rh ---------------------------------------------------
        {
            const unsigned* src = rhX + ((size_t)tl*4 + g)*8192;
#pragma unroll 2
            for (int it = 0; it < 4; ++it) {
                int idx = tid + it*512;
                u32x4 v = *(const u32x4*)&src[idx*4];
                int k = idx >> 1, n0 = (idx & 1) * 4;
#pragma unroll
                for (int e = 0; e < 4; ++e) {
                    shi[(n0+e)*1032 + k] = (unsigned short)(v[e] >> 16);
                    slo[(n0+e)*1032 + k] = (unsigned short)(v[e] & 0xffffu);
                }
            }
        }
        __syncthreads();

        // ---- phase B: own hc-cols + h update ----------------------------
        {
            f32x4 accC = {0,0,0,0};
            const unsigned short* bhC = WT  + (size_t)(2048 + cb + w*16 + l15)*2048 + 1024 + l4*8;
            const unsigned short* blC = Wlo + (size_t)(2048 + cb + w*16 + l15)*1024 + l4*8;
            for (int kq = 0; kq < 32; ++kq) {
                const int ka = kq*32 + l4*8;
                s16x8 ah = *(const s16x8*)&shi[l15*1032 + ka];
                s16x8 al = *(const s16x8*)&slo[l15*1032 + ka];
                s16x8 bh = *(const s16x8*)(bhC + kq*32);
                s16x8 bl = *(const s16x8*)(blC + kq*32);
                accC = __builtin_amdgcn_mfma_f32_16x16x32_bf16(ah, bh, accC, 0,0,0);
                accC = __builtin_amdgcn_mfma_f32_16x16x32_bf16(al, bh, accC, 0,0,0);
                accC = __builtin_amdgcn_mfma_f32_16x16x32_bf16(ah, bl, accC, 0,0,0);
            }
            if (l4 < 2) {
                const int jl = w*16 + l15;
                u32x4 pk;
#pragma unroll
                for (int q = 0; q < 4; ++q) {
                    int nl = l4*4 + q;
                    size_t crow = (size_t)(((nsb+nl)<<5) + tl)*3072;
                    float v = accC[q] + chunk[crow + 2048 + cb + jl];
                    float hcv  = tanhf(v);
                    float hold = hf32[nl*128 + jl];
                    float uu   = uls [nl*128 + jl];
                    float hn = hold + uu*(hcv - hold);
                    hf32[nl*128 + jl] = hn;
                    unsigned short hi = f2b(hn);
                    unsigned short lo = f2b(hn - b2f(hi));
                    pk[q] = ((unsigned)hi << 16) | lo;
                    htR[((size_t)t*32 + (nsb+nl))*1024 + cb + jl] = hi;
                    if (tl == CT-1) hper[(size_t)b*1024 + nl*128 + jl] = hn;
                }
                st_dev_u32x4(&hX[(((size_t)tl*4 + g)*1024 + (cb+jl))*8 + l4*4], pk);
            }
        }
        // ---- barrier 2 --------------------------------------------------
        asm volatile("s_waitcnt vmcnt(0)" ::: "memory");
        __syncthreads(); ++bidx;
        if (tid == 0) bar_arrive(ownf);
        if (tid < 8) bar_wait(&flags[(unsigned)(g*8 + tid)*32], bidx);
        __syncthreads();
    }
}

// ---------------------------------------------------------------------------
// D1: bare atomic group-barrier x 64 iterations. 32 blocks x 512 thr.
// ---------------------------------------------------------------------------
__global__ __launch_bounds__(512)
void diag_bar(unsigned* __restrict__ flags2)
{
    const int tid = threadIdx.x;
    const int b   = blockIdx.x, g = b >> 3;
    unsigned bidx = 0;
    unsigned* ownf = &flags2[(unsigned)b*32];
    for (int it = 0; it < 64; ++it) {
        __syncthreads(); ++bidx;
        if (tid == 0) bar_arrive(ownf);
        if (tid < 8) bar_wait(&flags2[(unsigned)(g*8 + tid)*32], bidx);
        __syncthreads();
    }
}

// ---------------------------------------------------------------------------
// D2: 32 iterations of {write own 4KB sc1 -> barrier -> read 32KB cached ->
// barrier}. Mirrors one scan segment's exchange with zero compute.
// ---------------------------------------------------------------------------
__global__ __launch_bounds__(512)
void diag_xchg(unsigned* __restrict__ ring,      // rhX region, [32][4][8192]
               unsigned* __restrict__ flags2)
{
    const int tid = threadIdx.x;
    const int b   = blockIdx.x;
    const int p   = b & 7, g = b >> 3;
    unsigned bidx = 64;                          // continue after D1
    unsigned* ownf = &flags2[(unsigned)b*32];
    unsigned acc = 0;
    for (int it = 0; it < 32; ++it) {
        unsigned* slot = ring + ((size_t)it*4 + g)*8192;
        if (tid < 256) {
            u32x4 v = { (unsigned)(tid+it), 2u, 3u, 4u };
            st_dev_u32x4(&slot[(size_t)p*1024 + tid*4], v);
        }
        asm volatile("s_waitcnt vmcnt(0)" ::: "memory");
        __syncthreads(); ++bidx;
        if (tid == 0) bar_arrive(ownf);
        if (tid < 8) bar_wait(&flags2[(unsigned)(g*8 + tid)*32], bidx);
        __syncthreads();
#pragma unroll 2
        for (int itr = 0; itr < 4; ++itr) {
            u32x4 v = *(const u32x4*)&slot[(tid + itr*512)*4];
            acc += v[0] + v[1] + v[2] + v[3];
        }
        __syncthreads(); ++bidx;
        if (tid == 0) bar_arrive(ownf);
        if (tid < 8) bar_wait(&flags2[(unsigned)(g*8 + tid)*32], bidx);
        __syncthreads();
    }
    if (tid == 0) flags2[2048 + b] = acc;        // keep reads live
}

// ---- last_h ---------------------------------------------------------------
__global__ __launch_bounds__(256)
void k_lasth(const float* __restrict__ hper, float* __restrict__ dst)
{
    int i = blockIdx.x*256 + threadIdx.x;     // 32768
    int n = i >> 10, j = i & 1023;
    dst[i] = hper[(((size_t)(n >> 3)*8 + (j >> 7)))*1024 + (n & 7)*128 + (j & 127)];
}

// ---------------------------------------------------------------------------
extern "C" void kernel_launch(void* const* d_in, const int* in_sizes, int n_in,
                              void* d_out, int out_size, void* d_ws, size_t ws_size,
                              hipStream_t stream)
{
    const float* x       = (const float*)d_in[0];
    const float* prev_ht = (const float*)d_in[1];
    const float* weight  = (const float*)d_in[2];
    const float* bias    = (const float*)d_in[3];
    float* out = (float*)d_out;
    float* ws  = (float*)d_ws;

    // ws layout (float units):
    unsigned short* WT   = (unsigned short*)ws;                 // 6,291,456 f
    unsigned short* Wlo  = (unsigned short*)(ws + 6291456);     // 1,572,864 f
    unsigned short* htR  = (unsigned short*)(ws + 7864320);     // 8,388,608 f
    unsigned short* xbf  = (unsigned short*)(ws + 16252928);    // 8,388,608 f
    float* zone          = ws + 24641536;                       // 8,388,608 f
    float* chunk         = zone;                                //  3,145,728 f
    unsigned* hX         = (unsigned*)(zone + 3145728);         //  1,048,576 f
    unsigned* rhX        = (unsigned*)(zone + 4194304);         //  1,048,576 f
    unsigned short* rxbf = (unsigned short*)zone;               // overlay post-scan
    float* hper          = ws + 33030144;                       //     32,768 f
    unsigned* flags      = (unsigned*)(ws + 33062912);          //      8,192 f
    unsigned* flags2     = flags + 4096;                        // 2nd 16 KB half
    const size_t needed = (size_t)33071104 * 4;                 // 132.3 MB
    if (ws_size < needed) return;

    hipMemsetAsync(flags, 0, 32768, stream);
    k_wt <<<dim3(96,32), 256, 0, stream>>>(weight, WT);
    k_wlo<<<dim3(48,16), 256, 0, stream>>>(weight, Wlo);
    k_xbf<<<16384, 256, 0, stream>>>(x, xbf);

    for (int seg = 0; seg < 16; ++seg) {
        int t0 = seg * CT;
        int bidx0 = seg * (2*CT);
        gemm_mfma<1,0><<<dim3(24,8), 256, 0, stream>>>(
            xbf, nullptr, WT, chunk, 3072, bias, nullptr, nullptr, nullptr,
            1024, t0);
        const float* gc = chunk;
        const unsigned short* WTc = WT;
        const unsigned short* Wloc = Wlo;
        void* args[] = { (void*)&gc, (void*)&WTc, (void*)&Wloc, (void*)&prev_ht,
                         (void*)&hX, (void*)&rhX, (void*)&htR, (void*)&hper,
                         (void*)&flags, (void*)&t0, (void*)&bidx0 };
        hipLaunchCooperativeKernel((void*)scan_mfma5, dim3(32), dim3(512),
                                   args, 0, stream);
    }

    // ---- diagnostics (timed, appear as rocprof rows; no output impact) ----
    {
        void* a1[] = { (void*)&flags2 };
        hipLaunchCooperativeKernel((void*)diag_bar, dim3(32), dim3(512),
                                   a1, 0, stream);
        void* a2[] = { (void*)&rhX, (void*)&flags2 };
        hipLaunchCooperativeKernel((void*)diag_xchg, dim3(32), dim3(512),
                                   a2, 0, stream);
    }

    // depth urd: [x|ht] @ W[:,3072:5120] -> sig -> ud (d_out), rx (bf16)
    gemm_mfma<2,1><<<dim3(16,128), 256, 0, stream>>>(
        xbf, htR, WT + (size_t)3072*2048, nullptr, 0, bias + 3072,
        x, out, rxbf, 2048, 0);
    // depth hc: [rx|ht] @ W[:,5120:6144] -> tanh -> final out
    gemm_mfma<2,2><<<dim3(8,128), 256, 0, stream>>>(
        rxbf, htR, WT + (size_t)5120*2048, out, 1024, bias + 5120,
        x, out, nullptr, 2048, 0);

    k_lasth<<<128, 256, 0, stream>>>(hper, out + (size_t)16384*1024);
}

// Round 13
// 23940.511 us; speedup vs baseline: 1.0187x; 1.0187x over previous
//
#include <hip/hip_runtime.h>
#include <cmath>

// ---------------------------------------------------------------------------
// GridGRU on MI355X. Round 13: XCC_ID-measured slice assignment (4 blocks/XCD
// share ONE 1.5MB packed W slice -> L2-resident) + per-slice contiguous W
// pack. Scan structure/numerics = r12 (f32 state, 3-term hi/lo split MFMA).
// N=32, T=512, D=H=1024. weight (2048,6144) row-major f32, bias 6144.
// ---------------------------------------------------------------------------

#define LDW 6144
#define CT 32                      // timesteps per segment (16 segments)
typedef float  f32x4 __attribute__((ext_vector_type(4)));
typedef short  s16x8 __attribute__((ext_vector_type(8)));
typedef unsigned u32x4 __attribute__((ext_vector_type(4)));

__device__ __forceinline__ float sigf(float v){ return 1.f/(1.f+__expf(-v)); }
__device__ __forceinline__ unsigned short f2b(float f){
    unsigned u = __float_as_uint(f);
    return (unsigned short)((u + 0x7FFFu + ((u>>16)&1u)) >> 16);
}
__device__ __forceinline__ float b2f(unsigned short u){
    return __uint_as_float(((unsigned)u) << 16);
}

__device__ __forceinline__ void st_dev_u32x4(unsigned* p, u32x4 v){
    asm volatile("global_store_dwordx4 %0, %1, off sc1"
                 :: "v"(p), "v"(v) : "memory");
}
__device__ __forceinline__ unsigned a_add(unsigned* p, unsigned v){
    return __hip_atomic_fetch_add(p, v, __ATOMIC_RELAXED,
                                  __HIP_MEMORY_SCOPE_AGENT);
}

// ---- WT[j][k] = bf16(weight[k][j]); j<6144, k<2048 (GEMMs) -----------------
__global__ __launch_bounds__(256)
void k_wt(const float* __restrict__ w, unsigned short* __restrict__ wt)
{
    __shared__ float t[64][65];
    const int j0 = blockIdx.x*64, k0 = blockIdx.y*64;
    for (int i = threadIdx.x; i < 4096; i += 256) {
        int r = i>>6, c = i&63;
        t[r][c] = w[(size_t)(k0+r)*LDW + j0 + c];
    }
    __syncthreads();
    for (int i = threadIdx.x; i < 4096; i += 256) {
        int jr = i>>6, kc = i&63;
        wt[(size_t)(j0+jr)*2048 + k0 + kc] = f2b(t[kc][jr]);
    }
}

// ---- Wpk: per-slice packed scan weights ------------------------------------
// Wpk[p][gi][c][k]=hi, [c][1024+k]=lo; p<8 slice, gi<3 gate, c<128 col,
// k<1024 over weight rows 1024..2047; col j = gi*1024 + p*128 + c.
__global__ __launch_bounds__(256)
void k_wpack(const float* __restrict__ w, unsigned short* __restrict__ wpk)
{
    __shared__ float t[64][65];
    const int j0 = blockIdx.x*64, k0 = blockIdx.y*64;   // j<3072, k<1024
    for (int i = threadIdx.x; i < 4096; i += 256) {
        int r = i>>6, c = i&63;
        t[r][c] = w[(size_t)(1024+k0+r)*LDW + j0 + c];
    }
    __syncthreads();
    for (int i = threadIdx.x; i < 4096; i += 256) {
        int jr = i>>6, kc = i&63;
        int j = j0 + jr, k = k0 + kc;
        float v = t[kc][jr];
        unsigned short hi = f2b(v);
        unsigned short lo = f2b(v - b2f(hi));
        int gi = j >> 10, rem = j & 1023, p = rem >> 7, c = rem & 127;
        size_t base = (size_t)p*786432 + (size_t)gi*262144 + (size_t)c*2048;
        wpk[base + k]        = hi;
        wpk[base + 1024 + k] = lo;
    }
}

// ---- x (f32) -> bf16 -------------------------------------------------------
__global__ __launch_bounds__(256)
void k_xbf(const float* __restrict__ x, unsigned short* __restrict__ o)
{
    long i = ((long)blockIdx.x*256 + threadIdx.x)*4;
    float4 v = *(const float4*)&x[i];
    ushort4 r = { f2b(v.x), f2b(v.y), f2b(v.z), f2b(v.w) };
    *(ushort4*)&o[i] = r;
}

// ---------------------------------------------------------------------------
// bf16 MFMA GEMM (validated rounds 3-12).
// ---------------------------------------------------------------------------
template<int AMODE, int EMODE>
__global__ __launch_bounds__(256)
void gemm_mfma(const unsigned short* __restrict__ A1,
               const unsigned short* __restrict__ A2,
               const unsigned short* __restrict__ Bw,
               float* __restrict__ C, int ldc,
               const float* __restrict__ bias,
               const float* __restrict__ X,
               float* __restrict__ UD,
               unsigned short* __restrict__ RX,
               int K, int t0)
{
    __shared__ unsigned short Als[128*32];
    __shared__ unsigned short Bls[128*32];
    const int tid = threadIdx.x;
    const int m_base = blockIdx.y*128;
    const int n_base = blockIdx.x*128;
    const int row0 = tid>>2, row1 = row0+64, quad = tid&3;
    const int wv = tid>>6, lane = tid&63;
    const int wr = (wv>>1)*64, wc = (wv&1)*64;
    const int l15 = lane&15, l4 = lane>>4;

    f32x4 acc[4][4] = {};

    for (int k0 = 0; k0 < K; k0 += 32) {
        const int kq = k0 + quad*8;
        s16x8 a0, a1, b0, b1;
        {
            long r0 = m_base + row0, r1 = m_base + row1;
            const unsigned short *p0, *p1;
            if (AMODE == 1) {
                long g0 = (r0>>5)*512 + t0 + (r0&31);
                long g1 = (r1>>5)*512 + t0 + (r1&31);
                p0 = A1 + g0*1024 + kq; p1 = A1 + g1*1024 + kq;
            } else if (AMODE == 2 && k0 >= 1024) {
                size_t o0 = ((size_t)(r0 & 511)*32 + (r0 >> 9))*1024 + (kq-1024);
                size_t o1 = ((size_t)(r1 & 511)*32 + (r1 >> 9))*1024 + (kq-1024);
                p0 = A2 + o0; p1 = A2 + o1;
            } else {
                p0 = A1 + r0*1024 + kq; p1 = A1 + r1*1024 + kq;
            }
            a0 = *(const s16x8*)p0; a1 = *(const s16x8*)p1;
        }
        b0 = *(const s16x8*)(Bw + (size_t)(n_base+row0)*2048 + kq);
        b1 = *(const s16x8*)(Bw + (size_t)(n_base+row1)*2048 + kq);
        __syncthreads();
        *(s16x8*)&Als[row0*32 + quad*8] = a0;
        *(s16x8*)&Als[row1*32 + quad*8] = a1;
        *(s16x8*)&Bls[row0*32 + quad*8] = b0;
        *(s16x8*)&Bls[row1*32 + quad*8] = b1;
        __syncthreads();
        s16x8 af[4], bfr[4];
#pragma unroll
        for (int i = 0; i < 4; ++i) {
            af[i]  = *(const s16x8*)&Als[(wr + i*16 + l15)*32 + l4*8];
            bfr[i] = *(const s16x8*)&Bls[(wc + i*16 + l15)*32 + l4*8];
        }
#pragma unroll
        for (int mi = 0; mi < 4; ++mi)
#pragma unroll
            for (int ni = 0; ni < 4; ++ni)
                acc[mi][ni] = __builtin_amdgcn_mfma_f32_16x16x32_bf16(
                    af[mi], bfr[ni], acc[mi][ni], 0, 0, 0);
    }

#pragma unroll
    for (int mi = 0; mi < 4; ++mi)
#pragma unroll
    for (int ni = 0; ni < 4; ++ni)
#pragma unroll
    for (int q = 0; q < 4; ++q) {
        int row = m_base + wr + mi*16 + l4*4 + q;
        int col = n_base + wc + ni*16 + l15;
        float v = acc[mi][ni][q] + bias[col];
        if (EMODE == 0) {
            C[(size_t)row*ldc + col] = v;
        } else if (EMODE == 1) {
            float s = sigf(v);
            if (col < 1024) {
                UD[(size_t)row*1024 + col] = s;
            } else {
                int jj = col - 1024;
                RX[(size_t)row*1024 + jj] = f2b(s * X[(size_t)row*1024 + jj]);
            }
        } else {
            float hc = tanhf(v);
            float xv = X[(size_t)row*1024 + col];
            float ud = UD[(size_t)row*1024 + col];
            C[(size_t)row*1024 + col] = xv + ud*(hc - xv);
        }
    }
}

// ---------------------------------------------------------------------------
// Persistent scan with XCC_ID-based slot assignment.
// slot = p*4+g: p = W col-slice (all blocks on one XCD get same p), g =
// sample group (samples 8g..8g+7). Flags/hper/rings keyed by slot/g.
// ---------------------------------------------------------------------------
__global__ __launch_bounds__(512)
void scan_mfma6(const float* __restrict__ chunk,
                const unsigned short* __restrict__ Wpk,
                const float* __restrict__ prev_ht,
                unsigned* __restrict__ hX,          // [CT][4][1024][8] u32
                unsigned* __restrict__ rhX,         // [CT][4][1024][8] u32
                unsigned short* __restrict__ htR,   // [(t*32+n)*1024+j] bf16
                float* __restrict__ hper,           // [slot][8n][128] f32
                unsigned* __restrict__ flags,       // slot*32 stride
                unsigned* __restrict__ abar,
                unsigned* __restrict__ xcnt,        // [9]
                int t0, int bidx0, unsigned abar_target)
{
    __shared__ unsigned short shi[16*1032];
    __shared__ unsigned short slo[16*1032];
    __shared__ float hf32[1024];
    __shared__ float uls [1024];
    __shared__ int   sh_slot;
    __shared__ unsigned sh_fpos;
    const int tid = threadIdx.x;
    const int w   = tid >> 6;
    const int lane= tid & 63;
    const int l15 = lane & 15, l4 = lane >> 4;
    unsigned bidx = (unsigned)bidx0;

    // ---- slot assignment (per dispatch; placement-measured) ---------------
    if (tid == 0) {
        unsigned xcd;
        asm volatile("s_getreg_b32 %0, hwreg(HW_REG_XCC_ID)" : "=s"(xcd));
        xcd &= 7u;
        unsigned pos = a_add(&xcnt[xcd], 1u);
        int slot = (pos < 4u) ? (int)(xcd*4u + pos) : -1;
        unsigned fpos = 0u;
        if (slot < 0) fpos = a_add(&xcnt[8], 1u);
        sh_slot = slot; sh_fpos = fpos;
        a_add(abar, 1u);
        while (a_add(abar, 0u) < abar_target) __builtin_amdgcn_s_sleep(1);
        if (sh_slot < 0) {                     // deterministic spill fill
            unsigned want = sh_fpos, k = 0; int s2 = -1;
            for (int p2 = 0; p2 < 8 && s2 < 0; ++p2) {
                unsigned c = a_add(&xcnt[p2], 0u);
                if (c > 4u) c = 4u;
                for (unsigned g2 = c; g2 < 4u && s2 < 0; ++g2, ++k)
                    if (k == want) s2 = p2*4 + (int)g2;
            }
            sh_slot = s2;
        }
    }
    __syncthreads();
    const int slot = sh_slot;
    const int p = slot >> 2, g = slot & 3;
    const int cb  = p * 128;
    const int nsb = g * 8;
    unsigned* ownf = &flags[(unsigned)slot*32];
    const unsigned short* wbase = Wpk + (size_t)p*786432;

    for (int i = tid; i < 8*1032; i += 512) { shi[8*1032 + i] = 0; slo[8*1032 + i] = 0; }
    for (int i = tid; i < 1024; i += 512) {
        int nl = i >> 7, jl = i & 127;
        hf32[i] = (t0 == 0) ? prev_ht[(size_t)(nsb+nl)*1024 + cb + jl]
                            : hper[(size_t)slot*1024 + i];
    }

    for (int tl = 0; tl < CT; ++tl) {
        const int t = t0 + tl;

        // ---- stage h ----------------------------------------------------
        if (t == 0) {
#pragma unroll 2
            for (int it = 0; it < 4; ++it) {
                int idx = tid + it*512;
                int nl = idx >> 8, k4 = (idx & 255) * 4;
                f32x4 v = *(const f32x4*)&prev_ht[(size_t)(nsb+nl)*1024 + k4];
#pragma unroll
                for (int e = 0; e < 4; ++e) {
                    unsigned short hi = f2b(v[e]);
                    shi[nl*1032 + k4 + e] = hi;
                    slo[nl*1032 + k4 + e] = f2b(v[e] - b2f(hi));
                }
            }
        } else {
            int slotr = (tl == 0) ? (CT-1) : (tl-1);
            const unsigned* src = hX + ((size_t)slotr*4 + g)*8192;
#pragma unroll 2
            for (int it = 0; it < 4; ++it) {
                int idx = tid + it*512;
                u32x4 v = *(const u32x4*)&src[idx*4];
                int k = idx >> 1, n0 = (idx & 1) * 4;
#pragma unroll
                for (int e = 0; e < 4; ++e) {
                    shi[(n0+e)*1032 + k] = (unsigned short)(v[e] >> 16);
                    slo[(n0+e)*1032 + k] = (unsigned short)(v[e] & 0xffffu);
                }
            }
        }
        __syncthreads();

        // ---- phase A: own u-cols + r-cols -------------------------------
        {
            f32x4 accU = {0,0,0,0}, accR = {0,0,0,0};
            const unsigned short* bhU = wbase +          (size_t)(w*16 + l15)*2048 + l4*8;
            const unsigned short* bhR = wbase + 262144 + (size_t)(w*16 + l15)*2048 + l4*8;
            for (int kq = 0; kq < 32; ++kq) {
                const int ka = kq*32 + l4*8;
                s16x8 ah = *(const s16x8*)&shi[l15*1032 + ka];
                s16x8 al = *(const s16x8*)&slo[l15*1032 + ka];
                s16x8 buh = *(const s16x8*)(bhU + kq*32);
                s16x8 bul = *(const s16x8*)(bhU + 1024 + kq*32);
                s16x8 brh = *(const s16x8*)(bhR + kq*32);
                s16x8 brl = *(const s16x8*)(bhR + 1024 + kq*32);
                accU = __builtin_amdgcn_mfma_f32_16x16x32_bf16(ah, buh, accU, 0,0,0);
                accU = __builtin_amdgcn_mfma_f32_16x16x32_bf16(al, buh, accU, 0,0,0);
                accU = __builtin_amdgcn_mfma_f32_16x16x32_bf16(ah, bul, accU, 0,0,0);
                accR = __builtin_amdgcn_mfma_f32_16x16x32_bf16(ah, brh, accR, 0,0,0);
                accR = __builtin_amdgcn_mfma_f32_16x16x32_bf16(al, brh, accR, 0,0,0);
                accR = __builtin_amdgcn_mfma_f32_16x16x32_bf16(ah, brl, accR, 0,0,0);
            }
            if (l4 < 2) {
                const int jl = w*16 + l15;
                const int k  = cb + jl;
                u32x4 pk;
#pragma unroll
                for (int q = 0; q < 4; ++q) {
                    int nl = l4*4 + q;
                    size_t crow = (size_t)(((nsb+nl)<<5) + tl)*3072;
                    float vu = accU[q] + chunk[crow + cb + jl];
                    uls[nl*128 + jl] = sigf(vu);
                    float vr = accR[q] + chunk[crow + 1024 + k];
                    float s  = sigf(vr);
                    float hv = b2f(shi[nl*1032 + k]) + b2f(slo[nl*1032 + k]);
                    float rh = s * hv;
                    unsigned short hi = f2b(rh);
                    unsigned short lo = f2b(rh - b2f(hi));
                    pk[q] = ((unsigned)hi << 16) | lo;
                }
                st_dev_u32x4(&rhX[(((size_t)tl*4 + g)*1024 + k)*8 + l4*4], pk);
            }
        }
        // ---- barrier 1 (group of 8 slots p2*4+g) ------------------------
        asm volatile("s_waitcnt vmcnt(0)" ::: "memory");
        __syncthreads(); ++bidx;
        if (tid == 0) a_add(ownf, 1u);
        if (tid < 8) {
            unsigned* f = &flags[(unsigned)(tid*4 + g)*32];
            while (a_add(f, 0u) < bidx) __builtin_amdgcn_s_sleep(1);
        }
        __syncthreads();

        // ---- stage rh ---------------------------------------------------
        {
            const unsigned* src = rhX + ((size_t)tl*4 + g)*8192;
#pragma unroll 2
            for (int it = 0; it < 4; ++it) {
                int idx = tid + it*512;
                u32x4 v = *(const u32x4*)&src[idx*4];
                int k = idx >> 1, n0 = (idx & 1) * 4;
#pragma unroll
                for (int e = 0; e < 4; ++e) {
                    shi[(n0+e)*1032 + k] = (unsigned short)(v[e] >> 16);
                    slo[(n0+e)*1032 + k] = (unsigned short)(v[e] & 0xffffu);
                }
            }
        }
        __syncthreads();

        // ---- phase B: own hc-cols + h update ----------------------------
        {
            f32x4 accC = {0,0,0,0};
            const unsigned short* bhC = wbase + 524288 + (size_t)(w*16 + l15)*2048 + l4*8;
            for (int kq = 0; kq < 32; ++kq) {
                const int ka = kq*32 + l4*8;
                s16x8 ah = *(const s16x8*)&shi[l15*1032 + ka];
                s16x8 al = *(const s16x8*)&slo[l15*1032 + ka];
                s16x8 bh = *(const s16x8*)(bhC + kq*32);
                s16x8 bl = *(const s16x8*)(bhC + 1024 + kq*32);
                accC = __builtin_amdgcn_mfma_f32_16x16x32_bf16(ah, bh, accC, 0,0,0);
                accC = __builtin_amdgcn_mfma_f32_16x16x32_bf16(al, bh, accC, 0,0,0);
                accC = __builtin_amdgcn_mfma_f32_16x16x32_bf16(ah, bl, accC, 0,0,0);
            }
            if (l4 < 2) {
                const int jl = w*16 + l15;
                u32x4 pk;
#pragma unroll
                for (int q = 0; q < 4; ++q) {
                    int nl = l4*4 + q;
                    size_t crow = (size_t)(((nsb+nl)<<5) + tl)*3072;
                    float v = accC[q] + chunk[crow + 2048 + cb + jl];
                    float hcv  = tanhf(v);
                    float hold = hf32[nl*128 + jl];
                    float uu   = uls [nl*128 + jl];
                    float hn = hold + uu*(hcv - hold);
                    hf32[nl*128 + jl] = hn;
                    unsigned short hi = f2b(hn);
                    unsigned short lo = f2b(hn - b2f(hi));
                    pk[q] = ((unsigned)hi << 16) | lo;
                    htR[((size_t)t*32 + (nsb+nl))*1024 + cb + jl] = hi;
                    if (tl == CT-1) hper[(size_t)slot*1024 + nl*128 + jl] = hn;
                }
                st_dev_u32x4(&hX[(((size_t)tl*4 + g)*1024 + (cb+jl))*8 + l4*4], pk);
            }
        }
        // ---- barrier 2 --------------------------------------------------
        asm volatile("s_waitcnt vmcnt(0)" ::: "memory");
        __syncthreads(); ++bidx;
        if (tid == 0) a_add(ownf, 1u);
        if (tid < 8) {
            unsigned* f = &flags[(unsigned)(tid*4 + g)*32];
            while (a_add(f, 0u) < bidx) __builtin_amdgcn_s_sleep(1);
        }
        __syncthreads();
    }

    // ---- reset xcnt for next dispatch (all blocks past final barrier) ----
    if (slot == 0 && tid == 0)
        for (int i = 0; i < 9; ++i)
            __hip_atomic_store(&xcnt[i], 0u, __ATOMIC_RELAXED,
                               __HIP_MEMORY_SCOPE_AGENT);
}

// ---- last_h: hper keyed by slot=(p*4+g) ------------------------------------
__global__ __launch_bounds__(256)
void k_lasth(const float* __restrict__ hper, float* __restrict__ dst)
{
    int i = blockIdx.x*256 + threadIdx.x;     // 32768
    int n = i >> 10, j = i & 1023;
    int p = j >> 7, jl = j & 127, g = n >> 3, nl = n & 7;
    dst[i] = hper[((size_t)(p*4 + g))*1024 + nl*128 + jl];
}

// ---------------------------------------------------------------------------
extern "C" void kernel_launch(void* const* d_in, const int* in_sizes, int n_in,
                              void* d_out, int out_size, void* d_ws, size_t ws_size,
                              hipStream_t stream)
{
    const float* x       = (const float*)d_in[0];
    const float* prev_ht = (const float*)d_in[1];
    const float* weight  = (const float*)d_in[2];
    const float* bias    = (const float*)d_in[3];
    float* out = (float*)d_out;
    float* ws  = (float*)d_ws;

    // ws layout (float units):
    unsigned short* WT   = (unsigned short*)ws;                 // 6,291,456 f
    unsigned short* htR  = (unsigned short*)(ws + 6291456);     // 8,388,608 f
    unsigned short* xbf  = (unsigned short*)(ws + 14680064);    // 8,388,608 f
    float* zone          = ws + 23068672;                       // 8,388,608 f
    float* chunk         = zone;                                //  3,145,728 f
    unsigned* hX         = (unsigned*)(zone + 3145728);         //  1,048,576 f
    unsigned* rhX        = (unsigned*)(zone + 4194304);         //  1,048,576 f
    unsigned short* Wpk  = (unsigned short*)(zone + 5242880);   //  3,145,728 f
    unsigned short* rxbf = (unsigned short*)zone;               // overlay post-scan
    float* hper          = ws + 31457280;                       //     32,768 f
    unsigned* flags      = (unsigned*)(ws + 31490048);          //      8,192 f
    unsigned* abar       = flags + 1024;
    unsigned* xcnt       = flags + 1056;                        // [9]
    const size_t needed = (size_t)31498240 * 4;                 // 126.0 MB
    if (ws_size < needed) return;

    hipMemsetAsync(flags, 0, 32768, stream);
    k_wt   <<<dim3(96,32), 256, 0, stream>>>(weight, WT);
    k_wpack<<<dim3(48,16), 256, 0, stream>>>(weight, Wpk);
    k_xbf  <<<16384, 256, 0, stream>>>(x, xbf);

    for (int seg = 0; seg < 16; ++seg) {
        int t0 = seg * CT;
        int bidx0 = seg * (2*CT);
        unsigned abar_target = 32u * (unsigned)(seg + 1);
        gemm_mfma<1,0><<<dim3(24,8), 256, 0, stream>>>(
            xbf, nullptr, WT, chunk, 3072, bias, nullptr, nullptr, nullptr,
            1024, t0);
        const float* gc = chunk;
        const unsigned short* Wpkc = Wpk;
        void* args[] = { (void*)&gc, (void*)&Wpkc, (void*)&prev_ht,
                         (void*)&hX, (void*)&rhX, (void*)&htR, (void*)&hper,
                         (void*)&flags, (void*)&abar, (void*)&xcnt,
                         (void*)&t0, (void*)&bidx0, (void*)&abar_target };
        hipLaunchCooperativeKernel((void*)scan_mfma6, dim3(32), dim3(512),
                                   args, 0, stream);
    }

    // depth urd: [x|ht] @ W[:,3072:5120] -> sig -> ud (d_out), rx (bf16)
    gemm_mfma<2,1><<<dim3(16,128), 256, 0, stream>>>(
        xbf, htR, WT + (size_t)3072*2048, nullptr, 0, bias + 3072,
        x, out, rxbf, 2048, 0);
    // depth hc: [rx|ht] @ W[:,5120:6144] -> tanh -> final out
    gemm_mfma<2,2><<<dim3(8,128), 256, 0, stream>>>(
        rxbf, htR, WT + (size_t)5120*2048, out, 1024, bias + 5120,
        x, out, nullptr, 2048, 0);

    k_lasth<<<128, 256, 0, stream>>>(hper, out + (size_t)16384*1024);
}

// Round 16
// 19297.774 us; speedup vs baseline: 1.2638x; 1.2406x over previous
//
#include <hip/hip_runtime.h>
#include <cmath>

// ---------------------------------------------------------------------------
// GridGRU on MI355X. Round 16: revert to the round-9 validated kernel
// (best passing artifact, 19.3 ms). f32 recurrent state + split-bf16 (hi/lo)
// MFMA scan. 32-block flag-barrier persistent scan, virgin-ring cached
// exchange. N=32, T=512, D=H=1024. weight (2048,6144) row-major f32.
// ---------------------------------------------------------------------------

#define LDW 6144
#define CT 32                      // timesteps per segment (16 segments)
typedef float  f32x4 __attribute__((ext_vector_type(4)));
typedef short  s16x8 __attribute__((ext_vector_type(8)));

__device__ __forceinline__ float sigf(float v){ return 1.f/(1.f+__expf(-v)); }
__device__ __forceinline__ unsigned short f2b(float f){
    unsigned u = __float_as_uint(f);
    return (unsigned short)((u + 0x7FFFu + ((u>>16)&1u)) >> 16);
}
__device__ __forceinline__ float b2f(unsigned short u){
    return __uint_as_float(((unsigned)u) << 16);
}

// ---- system-coherent write-through / uncached helpers ---------------------
__device__ __forceinline__ void st_sc1(float* p, float v){
    asm volatile("global_store_dword %0, %1, off sc0 sc1"
                 :: "v"(p), "v"(v) : "memory");
}
__device__ __forceinline__ void st_sc_b16(unsigned short* p, unsigned v){
    asm volatile("global_store_short %0, %1, off sc0 sc1"
                 :: "v"(p), "v"(v) : "memory");
}
__device__ __forceinline__ void st_sc_u32(unsigned* p, unsigned v){
    asm volatile("global_store_dword %0, %1, off sc0 sc1"
                 :: "v"(p), "v"(v) : "memory");
}
__device__ __forceinline__ unsigned ld_sc_u32(const unsigned* p){
    unsigned v;
    asm volatile("global_load_dword %0, %1, off sc0 sc1\n\t"
                 "s_waitcnt vmcnt(0)"
                 : "=v"(v) : "v"(p) : "memory");
    return v;
}

// ---- WT[j][k] = bf16(weight[k][j]); j<6144, k<2048 -------------------------
__global__ __launch_bounds__(256)
void k_wt(const float* __restrict__ w, unsigned short* __restrict__ wt)
{
    __shared__ float t[64][65];
    const int j0 = blockIdx.x*64, k0 = blockIdx.y*64;
    for (int i = threadIdx.x; i < 4096; i += 256) {
        int r = i>>6, c = i&63;
        t[r][c] = w[(size_t)(k0+r)*LDW + j0 + c];
    }
    __syncthreads();
    for (int i = threadIdx.x; i < 4096; i += 256) {
        int jr = i>>6, kc = i&63;
        wt[(size_t)(j0+jr)*2048 + k0 + kc] = f2b(t[kc][jr]);
    }
}

// ---- Wlo[j][k] = bf16-residual of weight[1024+k][j]; j<3072, k<1024 --------
__global__ __launch_bounds__(256)
void k_wlo(const float* __restrict__ w, unsigned short* __restrict__ wlo)
{
    __shared__ float t[64][65];
    const int j0 = blockIdx.x*64, k0 = blockIdx.y*64;
    for (int i = threadIdx.x; i < 4096; i += 256) {
        int r = i>>6, c = i&63;
        t[r][c] = w[(size_t)(1024+k0+r)*LDW + j0 + c];
    }
    __syncthreads();
    for (int i = threadIdx.x; i < 4096; i += 256) {
        int jr = i>>6, kc = i&63;
        float v = t[kc][jr];
        unsigned short hi = f2b(v);
        wlo[(size_t)(j0+jr)*1024 + k0 + kc] = f2b(v - b2f(hi));
    }
}

// ---- x (f32) -> bf16 -------------------------------------------------------
__global__ __launch_bounds__(256)
void k_xbf(const float* __restrict__ x, unsigned short* __restrict__ o)
{
    long i = ((long)blockIdx.x*256 + threadIdx.x)*4;
    float4 v = *(const float4*)&x[i];
    ushort4 r = { f2b(v.x), f2b(v.y), f2b(v.z), f2b(v.w) };
    *(ushort4*)&o[i] = r;
}

// ---------------------------------------------------------------------------
// bf16 MFMA GEMM (validated rounds 3-13).
// AMODE 1 (gates, CT=32): row r -> x row (r>>5)*512 + t0 + (r&31).
// AMODE 2 concat-K: k>=1024 -> A2 = htR t-major: ((r&511)*32 + (r>>9))*1024.
// ---------------------------------------------------------------------------
template<int AMODE, int EMODE>
__global__ __launch_bounds__(256)
void gemm_mfma(const unsigned short* __restrict__ A1,
               const unsigned short* __restrict__ A2,
               const unsigned short* __restrict__ Bw,
               float* __restrict__ C, int ldc,
               const float* __restrict__ bias,
               const float* __restrict__ X,
               float* __restrict__ UD,
               unsigned short* __restrict__ RX,
               int K, int t0)
{
    __shared__ unsigned short Als[128*32];
    __shared__ unsigned short Bls[128*32];
    const int tid = threadIdx.x;
    const int m_base = blockIdx.y*128;
    const int n_base = blockIdx.x*128;
    const int row0 = tid>>2, row1 = row0+64, quad = tid&3;
    const int wv = tid>>6, lane = tid&63;
    const int wr = (wv>>1)*64, wc = (wv&1)*64;
    const int l15 = lane&15, l4 = lane>>4;

    f32x4 acc[4][4] = {};

    for (int k0 = 0; k0 < K; k0 += 32) {
        const int kq = k0 + quad*8;
        s16x8 a0, a1, b0, b1;
        {
            long r0 = m_base + row0, r1 = m_base + row1;
            const unsigned short *p0, *p1;
            if (AMODE == 1) {
                long g0 = (r0>>5)*512 + t0 + (r0&31);
                long g1 = (r1>>5)*512 + t0 + (r1&31);
                p0 = A1 + g0*1024 + kq; p1 = A1 + g1*1024 + kq;
            } else if (AMODE == 2 && k0 >= 1024) {
                size_t o0 = ((size_t)(r0 & 511)*32 + (r0 >> 9))*1024 + (kq-1024);
                size_t o1 = ((size_t)(r1 & 511)*32 + (r1 >> 9))*1024 + (kq-1024);
                p0 = A2 + o0; p1 = A2 + o1;
            } else {
                p0 = A1 + r0*1024 + kq; p1 = A1 + r1*1024 + kq;
            }
            a0 = *(const s16x8*)p0; a1 = *(const s16x8*)p1;
        }
        b0 = *(const s16x8*)(Bw + (size_t)(n_base+row0)*2048 + kq);
        b1 = *(const s16x8*)(Bw + (size_t)(n_base+row1)*2048 + kq);
        __syncthreads();
        *(s16x8*)&Als[row0*32 + quad*8] = a0;
        *(s16x8*)&Als[row1*32 + quad*8] = a1;
        *(s16x8*)&Bls[row0*32 + quad*8] = b0;
        *(s16x8*)&Bls[row1*32 + quad*8] = b1;
        __syncthreads();
        s16x8 af[4], bfr[4];
#pragma unroll
        for (int i = 0; i < 4; ++i) {
            af[i]  = *(const s16x8*)&Als[(wr + i*16 + l15)*32 + l4*8];
            bfr[i] = *(const s16x8*)&Bls[(wc + i*16 + l15)*32 + l4*8];
        }
#pragma unroll
        for (int mi = 0; mi < 4; ++mi)
#pragma unroll
            for (int ni = 0; ni < 4; ++ni)
                acc[mi][ni] = __builtin_amdgcn_mfma_f32_16x16x32_bf16(
                    af[mi], bfr[ni], acc[mi][ni], 0, 0, 0);
    }

#pragma unroll
    for (int mi = 0; mi < 4; ++mi)
#pragma unroll
    for (int ni = 0; ni < 4; ++ni)
#pragma unroll
    for (int q = 0; q < 4; ++q) {
        int row = m_base + wr + mi*16 + l4*4 + q;
        int col = n_base + wc + ni*16 + l15;
        float v = acc[mi][ni][q] + bias[col];
        if (EMODE == 0) {
            C[(size_t)row*ldc + col] = v;
        } else if (EMODE == 1) {
            float s = sigf(v);
            if (col < 1024) {
                UD[(size_t)row*1024 + col] = s;
            } else {
                int jj = col - 1024;
                RX[(size_t)row*1024 + jj] = f2b(s * X[(size_t)row*1024 + jj]);
            }
        } else {
            float hc = tanhf(v);
            float xv = X[(size_t)row*1024 + col];
            float ud = UD[(size_t)row*1024 + col];
            C[(size_t)row*1024 + col] = xv + ud*(hc - xv);
        }
    }
}

// ---------------------------------------------------------------------------
// Persistent scan: 32 blocks x 512 threads (8 waves), 32 steps/launch,
// 2 flag barriers/step. Recurrent state f32 (hf32 LDS + hi/lo exchange).
// Matmuls: 3-term split-bf16 MFMA (hi*Whi + lo*Whi + hi*Wlo) ~ f32 accurate.
// LDS rows padded to 1032 shorts (bank-conflict-free).
// ---------------------------------------------------------------------------
__global__ __launch_bounds__(512)
void scan_mfma2(const float* __restrict__ chunk,    // [32n*32tl][3072]
                const unsigned short* __restrict__ WT,
                const unsigned short* __restrict__ Wlo,
                const float* __restrict__ prev_ht,
                unsigned short* __restrict__ htR,   // [512][32][1024] hi
                unsigned short* __restrict__ hloR,  // [32][32][1024] lo ring
                unsigned short* __restrict__ rhiR,  // [32][32][1024]
                unsigned short* __restrict__ rloR,  // [32][32][1024]
                float* __restrict__ hper,           // [16][32][64]
                unsigned* __restrict__ flags,
                int t0, int bidx0)
{
    __shared__ unsigned short shi[32*1032];
    __shared__ unsigned short slo[32*1032];
    __shared__ float hf32[2048];
    __shared__ float uls [2048];
    const int tid  = threadIdx.x;
    const int b    = blockIdx.x;
    const bool isU = (b < 16);
    const int w    = tid >> 6;        // 0..7
    const int wcg  = w & 3;           // col group (16 cols)
    const int wn   = w >> 2;          // n half (16 rows)
    const int lane = tid & 63;
    const int l15  = lane & 15;
    const int l4   = lane >> 4;
    const int cb   = b * 64;
    unsigned bidx  = (unsigned)bidx0;

    if (isU) {
        for (int i = tid; i < 2048; i += 512) {
            int n = i >> 6, jl = i & 63;
            hf32[i] = (t0 == 0) ? prev_ht[n*1024 + cb + jl]
                                : hper[((size_t)b*32 + n)*64 + jl];
        }
    }

    for (int tl = 0; tl < CT; ++tl) {
        const int t = t0 + tl;

        // ---- stage h hi/lo --------------------------------------------
        if (t == 0) {
#pragma unroll 2
            for (int it = 0; it < 8; ++it) {
                int g = tid + it*512;          // 0..4095
                int n = g >> 7, kg = (g & 127) * 8;
                f32x4 a = *(const f32x4*)&prev_ht[n*1024 + kg];
                f32x4 c = *(const f32x4*)&prev_ht[n*1024 + kg + 4];
                s16x8 vh, vl;
#pragma unroll
                for (int e = 0; e < 4; ++e) {
                    unsigned short h1 = f2b(a[e]);
                    vh[e]   = (short)h1; vl[e]   = (short)f2b(a[e] - b2f(h1));
                    unsigned short h2 = f2b(c[e]);
                    vh[4+e] = (short)h2; vl[4+e] = (short)f2b(c[e] - b2f(h2));
                }
                *(s16x8*)&shi[n*1032 + kg] = vh;
                *(s16x8*)&slo[n*1032 + kg] = vl;
            }
        } else {
            const unsigned short* shp = htR  + (size_t)(t-1)*32768;
            const unsigned short* slp = hloR + (size_t)((tl-1)&(CT-1))*32768;
#pragma unroll 2
            for (int it = 0; it < 8; ++it) {
                int g = tid + it*512;
                int n = g >> 7, kg = (g & 127) * 8;
                *(s16x8*)&shi[n*1032 + kg] = *(const s16x8*)&shp[n*1024 + kg];
                *(s16x8*)&slo[n*1032 + kg] = *(const s16x8*)&slp[n*1024 + kg];
            }
        }
        __syncthreads();

        // ---- phase A: ur cols [cb, cb+64) -----------------------------
        {
            const int jb = cb + wcg*16;
            f32x4 acc = {0,0,0,0};
            const unsigned short* bph = WT  + (size_t)(jb + l15)*2048 + 1024 + l4*8;
            const unsigned short* bpl = Wlo + (size_t)(jb + l15)*1024 + l4*8;
            const int rbase = wn*16 + l15;
#pragma unroll
            for (int kq = 0; kq < 32; ++kq) {
                int ka = kq*32 + l4*8;
                s16x8 ah = *(const s16x8*)&shi[rbase*1032 + ka];
                s16x8 al = *(const s16x8*)&slo[rbase*1032 + ka];
                s16x8 bh = *(const s16x8*)(bph + kq*32);
                s16x8 bl = *(const s16x8*)(bpl + kq*32);
                acc = __builtin_amdgcn_mfma_f32_16x16x32_bf16(ah, bh, acc, 0,0,0);
                acc = __builtin_amdgcn_mfma_f32_16x16x32_bf16(al, bh, acc, 0,0,0);
                acc = __builtin_amdgcn_mfma_f32_16x16x32_bf16(ah, bl, acc, 0,0,0);
            }
            const int jcol = jb + l15;
#pragma unroll
            for (int q = 0; q < 4; ++q) {
                int n = wn*16 + l4*4 + q;
                float v = acc[q] + chunk[(size_t)((n<<5) + tl)*3072 + jcol];
                float s = sigf(v);
                if (isU) {
                    uls[n*64 + (jcol - cb)] = s;
                } else {
                    int jg = jcol - 1024;
                    float hv = b2f(shi[n*1032 + jg]) + b2f(slo[n*1032 + jg]);
                    float rh = s * hv;
                    unsigned short rhi = f2b(rh);
                    st_sc_b16(&rhiR[((size_t)tl*32 + n)*1024 + jg], rhi);
                    st_sc_b16(&rloR[((size_t)tl*32 + n)*1024 + jg],
                              f2b(rh - b2f(rhi)));
                }
            }
        }
        // ---- barrier 1 ------------------------------------------------
        __syncthreads(); ++bidx;
        if (tid == 0) st_sc_u32(&flags[(unsigned)b*32], bidx);
        if (tid < 32) {
            const unsigned* f = &flags[(unsigned)tid*32];
            while (ld_sc_u32(f) < bidx) __builtin_amdgcn_s_sleep(1);
        }
        __syncthreads();

        if (isU) {
            // ---- stage rh hi/lo --------------------------------------
            const unsigned short* rip = rhiR + (size_t)tl*32768;
            const unsigned short* rlp = rloR + (size_t)tl*32768;
#pragma unroll 2
            for (int it = 0; it < 8; ++it) {
                int g = tid + it*512;
                int n = g >> 7, kg = (g & 127) * 8;
                *(s16x8*)&shi[n*1032 + kg] = *(const s16x8*)&rip[n*1024 + kg];
                *(s16x8*)&slo[n*1032 + kg] = *(const s16x8*)&rlp[n*1024 + kg];
            }
            __syncthreads();
            // ---- phase B: hc cols [cb, cb+64) + h update -------------
            const int jb = cb + wcg*16;
            f32x4 acc = {0,0,0,0};
            const unsigned short* bph = WT  + (size_t)(2048 + jb + l15)*2048 + 1024 + l4*8;
            const unsigned short* bpl = Wlo + (size_t)(2048 + jb + l15)*1024 + l4*8;
            const int rbase = wn*16 + l15;
#pragma unroll
            for (int kq = 0; kq < 32; ++kq) {
                int ka = kq*32 + l4*8;
                s16x8 ah = *(const s16x8*)&shi[rbase*1032 + ka];
                s16x8 al = *(const s16x8*)&slo[rbase*1032 + ka];
                s16x8 bh = *(const s16x8*)(bph + kq*32);
                s16x8 bl = *(const s16x8*)(bpl + kq*32);
                acc = __builtin_amdgcn_mfma_f32_16x16x32_bf16(ah, bh, acc, 0,0,0);
                acc = __builtin_amdgcn_mfma_f32_16x16x32_bf16(al, bh, acc, 0,0,0);
                acc = __builtin_amdgcn_mfma_f32_16x16x32_bf16(ah, bl, acc, 0,0,0);
            }
#pragma unroll
            for (int q = 0; q < 4; ++q) {
                int n  = wn*16 + l4*4 + q;
                int jl = wcg*16 + l15, jg = cb + jl;
                float v = acc[q] + chunk[(size_t)((n<<5) + tl)*3072 + 2048 + jg];
                float hcv  = tanhf(v);
                float hold = hf32[n*64 + jl];
                float uu   = uls [n*64 + jl];
                float hn = hold + uu*(hcv - hold);
                hf32[n*64 + jl] = hn;
                unsigned short hi = f2b(hn);
                st_sc_b16(&htR [((size_t)t*32  + n)*1024 + jg], hi);
                st_sc_b16(&hloR[((size_t)tl*32 + n)*1024 + jg],
                          f2b(hn - b2f(hi)));
                if (tl == CT-1) st_sc1(&hper[((size_t)b*32 + n)*64 + jl], hn);
            }
        }
        // ---- barrier 2 ------------------------------------------------
        __syncthreads(); ++bidx;
        if (tid == 0) st_sc_u32(&flags[(unsigned)b*32], bidx);
        if (tid < 32) {
            const unsigned* f = &flags[(unsigned)tid*32];
            while (ld_sc_u32(f) < bidx) __builtin_amdgcn_s_sleep(1);
        }
        __syncthreads();
    }
}

// ---- last_h: out[n*1024+j] = hper[(j/64)*32 + n][j%64] ---------------------
__global__ __launch_bounds__(256)
void k_lasth(const float* __restrict__ hper, float* __restrict__ dst)
{
    int i = blockIdx.x*256 + threadIdx.x;     // 32768
    int n = i >> 10, j = i & 1023;
    dst[i] = hper[(((size_t)(j >> 6))*32 + n)*64 + (j & 63)];
}

// ---------------------------------------------------------------------------
extern "C" void kernel_launch(void* const* d_in, const int* in_sizes, int n_in,
                              void* d_out, int out_size, void* d_ws, size_t ws_size,
                              hipStream_t stream)
{
    const float* x       = (const float*)d_in[0];
    const float* prev_ht = (const float*)d_in[1];
    const float* weight  = (const float*)d_in[2];
    const float* bias    = (const float*)d_in[3];
    float* out = (float*)d_out;
    float* ws  = (float*)d_ws;

    // ws layout (float units):
    unsigned short* WT   = (unsigned short*)ws;                 // 6,291,456 f
    unsigned short* Wlo  = (unsigned short*)(ws + 6291456);     // 1,572,864 f
    unsigned short* htR  = (unsigned short*)(ws + 7864320);     // 8,388,608 f
    unsigned short* xbf  = (unsigned short*)(ws + 16252928);    // 8,388,608 f
    float* zone          = ws + 24641536;                       // 8,388,608 f
    float* chunk         = zone;                                //  3,145,728 f
    unsigned short* rhiR = (unsigned short*)(zone + 3145728);   //    524,288 f
    unsigned short* rloR = (unsigned short*)(zone + 3670016);   //    524,288 f
    unsigned short* hloR = (unsigned short*)(zone + 4194304);   //    524,288 f
    unsigned short* rxbf = (unsigned short*)zone;               // overlay post-scan
    float* hper          = ws + 33030144;                       //     32,768 f
    unsigned* flags      = (unsigned*)(ws + 33062912);          //      8,192 f
    const size_t needed = (size_t)33071104 * 4;                 // 132.3 MB
    if (ws_size < needed) return;

    hipMemsetAsync(flags, 0, 4096, stream);
    k_wt <<<dim3(96,32), 256, 0, stream>>>(weight, WT);
    k_wlo<<<dim3(48,16), 256, 0, stream>>>(weight, Wlo);
    k_xbf<<<16384, 256, 0, stream>>>(x, xbf);

    for (int seg = 0; seg < 16; ++seg) {
        int t0 = seg * CT;
        int bidx0 = seg * (2*CT);
        // gates chunk: x rows (n*512 + t0 + tl) @ W[:,0:3072] + bt
        gemm_mfma<1,0><<<dim3(24,8), 256, 0, stream>>>(
            xbf, nullptr, WT, chunk, 3072, bias, nullptr, nullptr, nullptr,
            1024, t0);
        const float* gc = chunk;
        const unsigned short* WTc = WT;
        const unsigned short* Wloc = Wlo;
        void* args[] = { (void*)&gc, (void*)&WTc, (void*)&Wloc, (void*)&prev_ht,
                         (void*)&htR, (void*)&hloR, (void*)&rhiR, (void*)&rloR,
                         (void*)&hper, (void*)&flags, (void*)&t0, (void*)&bidx0 };
        hipLaunchCooperativeKernel((void*)scan_mfma2, dim3(32), dim3(512),
                                   args, 0, stream);
    }

    // depth urd: [x|ht] @ W[:,3072:5120] -> sig -> ud (d_out), rx (bf16)
    gemm_mfma<2,1><<<dim3(16,128), 256, 0, stream>>>(
        xbf, htR, WT + (size_t)3072*2048, nullptr, 0, bias + 3072,
        x, out, rxbf, 2048, 0);
    // depth hc: [rx|ht] @ W[:,5120:6144] -> tanh -> final out
    gemm_mfma<2,2><<<dim3(8,128), 256, 0, stream>>>(
        rxbf, htR, WT + (size_t)5120*2048, out, 1024, bias + 5120,
        x, out, nullptr, 2048, 0);

    k_lasth<<<128, 256, 0, stream>>>(hper, out + (size_t)16384*1024);
}